// Round 3
// baseline (432.265 us; speedup 1.0000x reference)
//
#include <hip/hip_runtime.h>

#define OUT_F 4096   // compressed rows
#define IN_F  2048   // compressed cols
#define KLOG  4096   // logical k = 2*IN_F
#define NB    4096   // batch
typedef unsigned long long ull;

typedef __bf16 bf16x8 __attribute__((ext_vector_type(8)));
typedef short  s16x8  __attribute__((ext_vector_type(8)));
typedef float  f32x4  __attribute__((ext_vector_type(4)));

__device__ __forceinline__ unsigned short f2bf(float f) {
    unsigned int u = __float_as_uint(f);
    u += 0x7fffu + ((u >> 16) & 1u);
    return (unsigned short)(u >> 16);
}

__device__ __forceinline__ void gload_lds16(const void* g, void* l) {
    __builtin_amdgcn_global_load_lds(
        (const __attribute__((address_space(1))) unsigned int*)g,
        (__attribute__((address_space(3))) unsigned int*)l, 16, 0, 0);
}

// ---------- Pre-pass (one launch, three block ranges):
//   [0, 8192)      : decompress weight -> dense bf16 wsA[4096][4096]
//   [8192, 16384)  : convert input fp32 -> bf16 wsB[4096][4096]
//   [16384, 20480) : zero-fill sibling output rows (indices[r]^1), float4 coalesced
__global__ __launch_bounds__(256) void prep_kernel(
    const float* __restrict__ weight, const int* __restrict__ metadata,
    const float* __restrict__ input, const int* __restrict__ indices,
    unsigned short* __restrict__ wsA, unsigned short* __restrict__ wsB,
    float* __restrict__ out)
{
    const int b = blockIdx.x;
    if (b < 8192) {
        // weight: each thread handles 4 compressed elems (2 groups-of-4 logical), 16B out
        const int g = b * 256 + threadIdx.x;
        const int r = g >> 9;
        const int c = (g & 511) * 4;
        const float4 wv = *(const float4*)(weight   + (size_t)r * IN_F + c);
        const int4   mv = *(const int4*)  (metadata + (size_t)r * IN_F + c);
        ull v0 = ((ull)f2bf(wv.x) << (mv.x * 16)) | ((ull)f2bf(wv.y) << (mv.y * 16));
        ull v1 = ((ull)f2bf(wv.z) << (mv.z * 16)) | ((ull)f2bf(wv.w) << (mv.w * 16));
        ull* dst = (ull*)(wsA + (size_t)r * KLOG + 2 * c);
        dst[0] = v0; dst[1] = v1;
    } else if (b < 16384) {
        // input: each thread converts 8 fp32 -> 8 bf16 (16B store)
        const int g = (b - 8192) * 256 + threadIdx.x;
        const size_t off = (size_t)g * 8;
        const float4 f0 = *(const float4*)(input + off);
        const float4 f1 = *(const float4*)(input + off + 4);
        ull v0 =  (ull)f2bf(f0.x) | ((ull)f2bf(f0.y) << 16) |
                 ((ull)f2bf(f0.z) << 32) | ((ull)f2bf(f0.w) << 48);
        ull v1 =  (ull)f2bf(f1.x) | ((ull)f2bf(f1.y) << 16) |
                 ((ull)f2bf(f1.z) << 32) | ((ull)f2bf(f1.w) << 48);
        ull* dst = (ull*)(wsB + off);
        dst[0] = v0; dst[1] = v1;
    } else {
        // zero-fill sibling logical row for compressed row r = b - 16384
        const int r = b - 16384;
        const int zrow = indices[r] ^ 1;
        float4* dst = (float4*)(out + (size_t)zrow * NB) + threadIdx.x;
        const float4 z = {0.f, 0.f, 0.f, 0.f};
#pragma unroll
        for (int s = 0; s < 4; ++s) dst[s * 256] = z;
    }
}

// ---------- Main GEMM (m97 structure): 128x128 tile, BK=32, 16x16x32 bf16 MFMA,
//            global_load_lds width=16 staging; epilogue stores ONLY value rows. ----------
__global__ __launch_bounds__(256) void gemm_kernel(
    const unsigned short* __restrict__ wsA, const unsigned short* __restrict__ wsB,
    const int* __restrict__ indices, float* __restrict__ out)
{
    __shared__ __align__(16) unsigned short As[128 * 32];
    __shared__ __align__(16) unsigned short Bs[128 * 32];

    const int tid  = threadIdx.x;
    const int lane = tid & 63;
    const int wave = tid >> 6;
    const int wm   = wave >> 1;
    const int wn   = wave & 1;
    const int l15  = lane & 15;
    const int quad = lane >> 4;

    const int r0 = blockIdx.y * 128;
    const int b0 = blockIdx.x * 128;

    const int srow  = wave * 32 + (lane >> 2);   // staging row (call 0); call 1 adds +16
    const int scolh = (lane & 3) * 8;            // ushort offset within row
    const unsigned ldsA0 = wave * 2048;          // wave-uniform LDS byte base
    const unsigned short* gA = wsA + (size_t)(r0 + srow) * KLOG + scolh;
    const unsigned short* gB = wsB + (size_t)(b0 + srow) * KLOG + scolh;

    f32x4 acc[4][4];
#pragma unroll
    for (int i = 0; i < 4; ++i)
#pragma unroll
        for (int j = 0; j < 4; ++j)
            acc[i][j] = (f32x4){0.f, 0.f, 0.f, 0.f};

    for (int k0 = 0; k0 < KLOG; k0 += 32) {
        gload_lds16(gA + k0,             (char*)As + ldsA0);
        gload_lds16(gA + 16 * KLOG + k0, (char*)As + ldsA0 + 1024);
        gload_lds16(gB + k0,             (char*)Bs + ldsA0);
        gload_lds16(gB + 16 * KLOG + k0, (char*)Bs + ldsA0 + 1024);
        __syncthreads();

        bf16x8 a[4], b[4];
#pragma unroll
        for (int i = 0; i < 4; ++i)
            a[i] = __builtin_bit_cast(bf16x8,
                     *(const s16x8*)(As + (wm * 64 + i * 16 + l15) * 32 + quad * 8));
#pragma unroll
        for (int j = 0; j < 4; ++j)
            b[j] = __builtin_bit_cast(bf16x8,
                     *(const s16x8*)(Bs + (wn * 64 + j * 16 + l15) * 32 + quad * 8));
#pragma unroll
        for (int i = 0; i < 4; ++i)
#pragma unroll
            for (int j = 0; j < 4; ++j)
                acc[i][j] = __builtin_amdgcn_mfma_f32_16x16x32_bf16(
                                a[i], b[j], acc[i][j], 0, 0, 0);
        __syncthreads();
    }

    // epilogue: C/D row = quad*4+t, col = l15; store value rows only
#pragma unroll
    for (int i = 0; i < 4; ++i) {
#pragma unroll
        for (int t = 0; t < 4; ++t) {
            const int r = r0 + wm * 64 + i * 16 + quad * 4 + t;
            const size_t base = (size_t)indices[r] * NB;
#pragma unroll
            for (int j = 0; j < 4; ++j) {
                const int col = b0 + wn * 64 + j * 16 + l15;
                out[base + col] = acc[i][j][t];
            }
        }
    }
}

// ---------- Fallback (round-1 fused kernel) if ws is too small ----------
__global__ __launch_bounds__(256) void spmm_dt_fallback(
    const float* __restrict__ weight, const int* __restrict__ indices,
    const int* __restrict__ metadata, const float* __restrict__ input,
    float* __restrict__ out)
{
    __shared__ __align__(16) unsigned short As[128][32];
    __shared__ __align__(16) unsigned short Bs[128][32];
    const int tid = threadIdx.x, lane = tid & 63, wave = tid >> 6;
    const int wm = wave >> 1, wn = wave & 1, l15 = lane & 15, quad = lane >> 4;
    const int r0 = blockIdx.y * 128, b0 = blockIdx.x * 128;
    f32x4 acc[4][4];
#pragma unroll
    for (int i = 0; i < 4; ++i)
#pragma unroll
        for (int j = 0; j < 4; ++j) acc[i][j] = (f32x4){0.f, 0.f, 0.f, 0.f};
    const int srow = tid >> 3, sgrp = tid & 7;
    for (int kk = 0; kk < KLOG / 32; ++kk) {
        const int c0 = kk * 16, k0 = kk * 32;
#pragma unroll
        for (int s = 0; s < 4; ++s) {
            const int row = srow + s * 32;
            const size_t off = (size_t)(r0 + row) * IN_F + c0 + 2 * sgrp;
            const float2 w = *(const float2*)(weight + off);
            const int2  md = *(const int2*)(metadata + off);
            *(ull*)(&As[row][4 * sgrp]) =
                ((ull)f2bf(w.x) << (md.x * 16)) | ((ull)f2bf(w.y) << (md.y * 16));
        }
#pragma unroll
        for (int s = 0; s < 4; ++s) {
            const int row = srow + s * 32;
            const float4 f = *(const float4*)(&input[(size_t)(b0 + row) * KLOG + k0 + sgrp * 4]);
            *(ull*)(&Bs[row][sgrp * 4]) =
                 (ull)f2bf(f.x) | ((ull)f2bf(f.y) << 16) |
                ((ull)f2bf(f.z) << 32) | ((ull)f2bf(f.w) << 48);
        }
        __syncthreads();
        bf16x8 a[4], b[4];
#pragma unroll
        for (int i = 0; i < 4; ++i)
            a[i] = __builtin_bit_cast(bf16x8, *(const s16x8*)(&As[wm * 64 + i * 16 + l15][quad * 8]));
#pragma unroll
        for (int j = 0; j < 4; ++j)
            b[j] = __builtin_bit_cast(bf16x8, *(const s16x8*)(&Bs[wn * 64 + j * 16 + l15][quad * 8]));
#pragma unroll
        for (int i = 0; i < 4; ++i)
#pragma unroll
            for (int j = 0; j < 4; ++j)
                acc[i][j] = __builtin_amdgcn_mfma_f32_16x16x32_bf16(a[i], b[j], acc[i][j], 0, 0, 0);
        __syncthreads();
    }
#pragma unroll
    for (int i = 0; i < 4; ++i)
#pragma unroll
        for (int t = 0; t < 4; ++t) {
            const int r = r0 + wm * 64 + i * 16 + quad * 4 + t;
            const int L = indices[r];
            const size_t base = (size_t)L * NB, baseZ = (size_t)(L ^ 1) * NB;
#pragma unroll
            for (int j = 0; j < 4; ++j) {
                const int col = b0 + wn * 64 + j * 16 + l15;
                out[base + col] = acc[i][j][t];
                out[baseZ + col] = 0.0f;
            }
        }
}

extern "C" void kernel_launch(void* const* d_in, const int* in_sizes, int n_in,
                              void* d_out, int out_size, void* d_ws, size_t ws_size,
                              hipStream_t stream) {
    const float* weight   = (const float*)d_in[0];
    const int*   indices  = (const int*)d_in[1];
    const int*   metadata = (const int*)d_in[2];
    const float* input    = (const float*)d_in[3];
    float*       out      = (float*)d_out;

    const size_t needA = (size_t)OUT_F * KLOG * 2;  // 32 MB
    const size_t needB = (size_t)NB * KLOG * 2;     // 32 MB
    if (ws_size >= needA + needB) {
        unsigned short* wsA = (unsigned short*)d_ws;
        unsigned short* wsB = wsA + (size_t)OUT_F * KLOG;
        prep_kernel<<<dim3(20480), dim3(256), 0, stream>>>(
            weight, metadata, input, indices, wsA, wsB, out);
        gemm_kernel<<<dim3(NB / 128, OUT_F / 128), dim3(256), 0, stream>>>(wsA, wsB, indices, out);
    } else {
        spmm_dt_fallback<<<dim3(NB / 128, OUT_F / 128), dim3(256), 0, stream>>>(
            weight, indices, metadata, input, out);
    }
}

// Round 4
// 390.998 us; speedup vs baseline: 1.1055x; 1.1055x over previous
//
#include <hip/hip_runtime.h>

#define OUT_F 4096   // compressed rows
#define IN_F  2048   // compressed cols
#define KLOG  4096   // logical k = 2*IN_F
#define NB    4096   // batch
typedef unsigned long long ull;
typedef ull ullx2 __attribute__((ext_vector_type(2)));

typedef __bf16 bf16x8 __attribute__((ext_vector_type(8)));
typedef short  s16x8  __attribute__((ext_vector_type(8)));
typedef float  f32x4  __attribute__((ext_vector_type(4)));
typedef float  f32x16 __attribute__((ext_vector_type(16)));

__device__ __forceinline__ unsigned short f2bf(float f) {
    unsigned int u = __float_as_uint(f);
    u += 0x7fffu + ((u >> 16) & 1u);
    return (unsigned short)(u >> 16);
}

__device__ __forceinline__ void gload_lds16(const void* g, void* l) {
    __builtin_amdgcn_global_load_lds(
        (const __attribute__((address_space(1))) unsigned int*)g,
        (__attribute__((address_space(3))) unsigned int*)l, 16, 0, 0);
}

// ---------- Pre-pass: [0,4096) decompress weight -> bf16 wsA; [4096,8192) input -> bf16 wsB.
//            32B of output per thread. ----------
__global__ __launch_bounds__(256) void prep_kernel(
    const float* __restrict__ weight, const int* __restrict__ metadata,
    const float* __restrict__ input,
    unsigned short* __restrict__ wsA, unsigned short* __restrict__ wsB)
{
    const int b = blockIdx.x;
    if (b < 4096) {
        // 8 compressed elems / thread -> 16 logical bf16 (32B)
        const int g = b * 256 + threadIdx.x;
        const int r = g >> 8;            // 256 threads per row (2048/8)
        const int c = (g & 255) * 8;
        const size_t off = (size_t)r * IN_F + c;
        const float4 w0 = *(const float4*)(weight + off);
        const float4 w1 = *(const float4*)(weight + off + 4);
        const int4   m0 = *(const int4*)(metadata + off);
        const int4   m1 = *(const int4*)(metadata + off + 4);
        ullx2 v01, v23;
        v01.x = ((ull)f2bf(w0.x) << (m0.x * 16)) | ((ull)f2bf(w0.y) << (m0.y * 16));
        v01.y = ((ull)f2bf(w0.z) << (m0.z * 16)) | ((ull)f2bf(w0.w) << (m0.w * 16));
        v23.x = ((ull)f2bf(w1.x) << (m1.x * 16)) | ((ull)f2bf(w1.y) << (m1.y * 16));
        v23.y = ((ull)f2bf(w1.z) << (m1.z * 16)) | ((ull)f2bf(w1.w) << (m1.w * 16));
        ull* dst = (ull*)(wsA + (size_t)r * KLOG + 2 * c);
        *(ullx2*)(dst)     = v01;
        *(ullx2*)(dst + 2) = v23;
    } else {
        // 16 fp32 -> 16 bf16 / thread (32B)
        const int g = (b - 4096) * 256 + threadIdx.x;
        const size_t off = (size_t)g * 16;
        const float4 f0 = *(const float4*)(input + off);
        const float4 f1 = *(const float4*)(input + off + 4);
        const float4 f2 = *(const float4*)(input + off + 8);
        const float4 f3 = *(const float4*)(input + off + 12);
        ullx2 v01, v23;
        v01.x =  (ull)f2bf(f0.x) | ((ull)f2bf(f0.y) << 16) | ((ull)f2bf(f0.z) << 32) | ((ull)f2bf(f0.w) << 48);
        v01.y =  (ull)f2bf(f1.x) | ((ull)f2bf(f1.y) << 16) | ((ull)f2bf(f1.z) << 32) | ((ull)f2bf(f1.w) << 48);
        v23.x =  (ull)f2bf(f2.x) | ((ull)f2bf(f2.y) << 16) | ((ull)f2bf(f2.z) << 32) | ((ull)f2bf(f2.w) << 48);
        v23.y =  (ull)f2bf(f3.x) | ((ull)f2bf(f3.y) << 16) | ((ull)f2bf(f3.z) << 32) | ((ull)f2bf(f3.w) << 48);
        ull* dst = (ull*)(wsB + off);
        *(ullx2*)(dst)     = v01;
        *(ullx2*)(dst + 2) = v23;
    }
}

// ---------- Main GEMM: 128x128 tile, BK=32, 32x32x16 bf16 MFMA (8 MFMA/iter/wave),
//            XOR-4 swizzled LDS (uniform banks), global_load_lds width=16 staging,
//            scatter epilogue with sibling-row zeroing. ----------
__global__ __launch_bounds__(256) void gemm_kernel(
    const unsigned short* __restrict__ wsA, const unsigned short* __restrict__ wsB,
    const int* __restrict__ indices, float* __restrict__ out)
{
    __shared__ __align__(16) unsigned short As[128 * 32];
    __shared__ __align__(16) unsigned short Bs[128 * 32];

    const int tid  = threadIdx.x;
    const int lane = tid & 63;
    const int wave = tid >> 6;
    const int wm   = wave >> 1;   // row quadrant (64 rows)
    const int wn   = wave & 1;    // col quadrant (64 cols)
    const int l31  = lane & 31;
    const int h    = lane >> 5;   // k-half of fragment

    const int r0 = blockIdx.y * 128;
    const int b0 = blockIdx.x * 128;

    // staging: lane -> LDS row wave*32+call*16+(lane>>2), phys col16 = lane&3.
    // swizzle phys = logical ^ (row&3)  =>  source logical col16 = (lane&3)^((lane>>2)&3).
    const int srow   = wave * 32 + (lane >> 2);
    const int scol16 = (lane & 3) ^ ((lane >> 2) & 3);
    const unsigned ldsOff = wave * 2048;
    const unsigned short* gA = wsA + (size_t)(r0 + srow) * KLOG + scol16 * 8;
    const unsigned short* gB = wsB + (size_t)(b0 + srow) * KLOG + scol16 * 8;

    f32x16 acc[2][2];
#pragma unroll
    for (int i = 0; i < 2; ++i)
#pragma unroll
        for (int j = 0; j < 2; ++j)
#pragma unroll
            for (int e = 0; e < 16; ++e) acc[i][j][e] = 0.f;

    for (int k0 = 0; k0 < KLOG; k0 += 32) {
        gload_lds16(gA + k0,             (char*)As + ldsOff);
        gload_lds16(gA + 16 * KLOG + k0, (char*)As + ldsOff + 1024);
        gload_lds16(gB + k0,             (char*)Bs + ldsOff);
        gload_lds16(gB + 16 * KLOG + k0, (char*)Bs + ldsOff + 1024);
        __syncthreads();

        // fragments: A[m=l31][k=h*8+j] at logical col16 = kh*2+h, phys = logical^(row&3)
        bf16x8 a[2][2], b[2][2];
#pragma unroll
        for (int mi = 0; mi < 2; ++mi)
#pragma unroll
            for (int kh = 0; kh < 2; ++kh) {
                const int row = wm * 64 + mi * 32 + l31;
                const int phys = (kh * 2 + h) ^ (row & 3);
                a[mi][kh] = __builtin_bit_cast(bf16x8, *(const s16x8*)(As + row * 32 + phys * 8));
            }
#pragma unroll
        for (int nj = 0; nj < 2; ++nj)
#pragma unroll
            for (int kh = 0; kh < 2; ++kh) {
                const int row = wn * 64 + nj * 32 + l31;
                const int phys = (kh * 2 + h) ^ (row & 3);
                b[nj][kh] = __builtin_bit_cast(bf16x8, *(const s16x8*)(Bs + row * 32 + phys * 8));
            }

#pragma unroll
        for (int kh = 0; kh < 2; ++kh)
#pragma unroll
            for (int mi = 0; mi < 2; ++mi)
#pragma unroll
                for (int nj = 0; nj < 2; ++nj)
                    acc[mi][nj] = __builtin_amdgcn_mfma_f32_32x32x16_bf16(
                                      a[mi][kh], b[nj][kh], acc[mi][nj], 0, 0, 0);
        __syncthreads();
    }

    // epilogue: C/D (32x32): col = l31, row = (reg&3) + 8*(reg>>2) + 4*h  [m74/m101]
#pragma unroll
    for (int mi = 0; mi < 2; ++mi) {
#pragma unroll
        for (int reg = 0; reg < 16; ++reg) {
            const int rloc = wm * 64 + mi * 32 + (reg & 3) + 8 * (reg >> 2) + 4 * h;
            const int L = indices[r0 + rloc];
            const size_t base  = (size_t)L * NB;
            const size_t baseZ = (size_t)(L ^ 1) * NB;
#pragma unroll
            for (int nj = 0; nj < 2; ++nj) {
                const int col = b0 + wn * 64 + nj * 32 + l31;
                out[base  + col] = acc[mi][nj][reg];
                out[baseZ + col] = 0.0f;
            }
        }
    }
}

// ---------- Fallback (round-1 fused kernel) if ws is too small ----------
__global__ __launch_bounds__(256) void spmm_dt_fallback(
    const float* __restrict__ weight, const int* __restrict__ indices,
    const int* __restrict__ metadata, const float* __restrict__ input,
    float* __restrict__ out)
{
    __shared__ __align__(16) unsigned short As[128][32];
    __shared__ __align__(16) unsigned short Bs[128][32];
    const int tid = threadIdx.x, lane = tid & 63, wave = tid >> 6;
    const int wm = wave >> 1, wn = wave & 1, l15 = lane & 15, quad = lane >> 4;
    const int r0 = blockIdx.y * 128, b0 = blockIdx.x * 128;
    f32x4 acc[4][4];
#pragma unroll
    for (int i = 0; i < 4; ++i)
#pragma unroll
        for (int j = 0; j < 4; ++j) acc[i][j] = (f32x4){0.f, 0.f, 0.f, 0.f};
    const int srow = tid >> 3, sgrp = tid & 7;
    for (int kk = 0; kk < KLOG / 32; ++kk) {
        const int c0 = kk * 16, k0 = kk * 32;
#pragma unroll
        for (int s = 0; s < 4; ++s) {
            const int row = srow + s * 32;
            const size_t off = (size_t)(r0 + row) * IN_F + c0 + 2 * sgrp;
            const float2 w = *(const float2*)(weight + off);
            const int2  md = *(const int2*)(metadata + off);
            *(ull*)(&As[row][4 * sgrp]) =
                ((ull)f2bf(w.x) << (md.x * 16)) | ((ull)f2bf(w.y) << (md.y * 16));
        }
#pragma unroll
        for (int s = 0; s < 4; ++s) {
            const int row = srow + s * 32;
            const float4 f = *(const float4*)(&input[(size_t)(b0 + row) * KLOG + k0 + sgrp * 4]);
            *(ull*)(&Bs[row][sgrp * 4]) =
                 (ull)f2bf(f.x) | ((ull)f2bf(f.y) << 16) |
                ((ull)f2bf(f.z) << 32) | ((ull)f2bf(f.w) << 48);
        }
        __syncthreads();
        bf16x8 a[4], b[4];
#pragma unroll
        for (int i = 0; i < 4; ++i)
            a[i] = __builtin_bit_cast(bf16x8, *(const s16x8*)(&As[wm * 64 + i * 16 + l15][quad * 8]));
#pragma unroll
        for (int j = 0; j < 4; ++j)
            b[j] = __builtin_bit_cast(bf16x8, *(const s16x8*)(&Bs[wn * 64 + j * 16 + l15][quad * 8]));
#pragma unroll
        for (int i = 0; i < 4; ++i)
#pragma unroll
            for (int j = 0; j < 4; ++j)
                acc[i][j] = __builtin_amdgcn_mfma_f32_16x16x32_bf16(a[i], b[j], acc[i][j], 0, 0, 0);
        __syncthreads();
    }
#pragma unroll
    for (int i = 0; i < 4; ++i)
#pragma unroll
        for (int t = 0; t < 4; ++t) {
            const int r = r0 + wm * 64 + i * 16 + quad * 4 + t;
            const int L = indices[r];
            const size_t base = (size_t)L * NB, baseZ = (size_t)(L ^ 1) * NB;
#pragma unroll
            for (int j = 0; j < 4; ++j) {
                const int col = b0 + wn * 64 + j * 16 + l15;
                out[base + col] = acc[i][j][t];
                out[baseZ + col] = 0.0f;
            }
        }
}

extern "C" void kernel_launch(void* const* d_in, const int* in_sizes, int n_in,
                              void* d_out, int out_size, void* d_ws, size_t ws_size,
                              hipStream_t stream) {
    const float* weight   = (const float*)d_in[0];
    const int*   indices  = (const int*)d_in[1];
    const int*   metadata = (const int*)d_in[2];
    const float* input    = (const float*)d_in[3];
    float*       out      = (float*)d_out;

    const size_t needA = (size_t)OUT_F * KLOG * 2;  // 32 MB
    const size_t needB = (size_t)NB * KLOG * 2;     // 32 MB
    if (ws_size >= needA + needB) {
        unsigned short* wsA = (unsigned short*)d_ws;
        unsigned short* wsB = wsA + (size_t)OUT_F * KLOG;
        prep_kernel<<<dim3(8192), dim3(256), 0, stream>>>(weight, metadata, input, wsA, wsB);
        gemm_kernel<<<dim3(NB / 128, OUT_F / 128), dim3(256), 0, stream>>>(wsA, wsB, indices, out);
    } else {
        spmm_dt_fallback<<<dim3(NB / 128, OUT_F / 128), dim3(256), 0, stream>>>(
            weight, indices, metadata, input, out);
    }
}

// Round 5
// 387.283 us; speedup vs baseline: 1.1161x; 1.0096x over previous
//
#include <hip/hip_runtime.h>

#define OUT_F 4096   // compressed rows
#define IN_F  2048   // compressed cols
#define KLOG  4096   // logical k = 2*IN_F
#define NB    4096   // batch
typedef unsigned long long ull;
typedef ull ullx2 __attribute__((ext_vector_type(2)));

typedef __bf16 bf16x8 __attribute__((ext_vector_type(8)));
typedef short  s16x8  __attribute__((ext_vector_type(8)));
typedef float  f32x4  __attribute__((ext_vector_type(4)));
typedef float  f32x16 __attribute__((ext_vector_type(16)));

__device__ __forceinline__ unsigned short f2bf(float f) {
    unsigned int u = __float_as_uint(f);
    u += 0x7fffu + ((u >> 16) & 1u);
    return (unsigned short)(u >> 16);
}

__device__ __forceinline__ void gload_lds16(const void* g, void* l) {
    __builtin_amdgcn_global_load_lds(
        (const __attribute__((address_space(1))) unsigned int*)g,
        (__attribute__((address_space(3))) unsigned int*)l, 16, 0, 0);
}

// ---------- Pre-pass: [0,4096) decompress weight -> bf16 wsA; [4096,8192) input -> bf16 wsB.
//            32B of output per thread. ----------
__global__ __launch_bounds__(256) void prep_kernel(
    const float* __restrict__ weight, const int* __restrict__ metadata,
    const float* __restrict__ input,
    unsigned short* __restrict__ wsA, unsigned short* __restrict__ wsB)
{
    const int b = blockIdx.x;
    if (b < 4096) {
        const int g = b * 256 + threadIdx.x;
        const int r = g >> 8;
        const int c = (g & 255) * 8;
        const size_t off = (size_t)r * IN_F + c;
        const float4 w0 = *(const float4*)(weight + off);
        const float4 w1 = *(const float4*)(weight + off + 4);
        const int4   m0 = *(const int4*)(metadata + off);
        const int4   m1 = *(const int4*)(metadata + off + 4);
        ullx2 v01, v23;
        v01.x = ((ull)f2bf(w0.x) << (m0.x * 16)) | ((ull)f2bf(w0.y) << (m0.y * 16));
        v01.y = ((ull)f2bf(w0.z) << (m0.z * 16)) | ((ull)f2bf(w0.w) << (m0.w * 16));
        v23.x = ((ull)f2bf(w1.x) << (m1.x * 16)) | ((ull)f2bf(w1.y) << (m1.y * 16));
        v23.y = ((ull)f2bf(w1.z) << (m1.z * 16)) | ((ull)f2bf(w1.w) << (m1.w * 16));
        ull* dst = (ull*)(wsA + (size_t)r * KLOG + 2 * c);
        *(ullx2*)(dst)     = v01;
        *(ullx2*)(dst + 2) = v23;
    } else {
        const int g = (b - 4096) * 256 + threadIdx.x;
        const size_t off = (size_t)g * 16;
        const float4 f0 = *(const float4*)(input + off);
        const float4 f1 = *(const float4*)(input + off + 4);
        const float4 f2 = *(const float4*)(input + off + 8);
        const float4 f3 = *(const float4*)(input + off + 12);
        ullx2 v01, v23;
        v01.x =  (ull)f2bf(f0.x) | ((ull)f2bf(f0.y) << 16) | ((ull)f2bf(f0.z) << 32) | ((ull)f2bf(f0.w) << 48);
        v01.y =  (ull)f2bf(f1.x) | ((ull)f2bf(f1.y) << 16) | ((ull)f2bf(f1.z) << 32) | ((ull)f2bf(f1.w) << 48);
        v23.x =  (ull)f2bf(f2.x) | ((ull)f2bf(f2.y) << 16) | ((ull)f2bf(f2.z) << 32) | ((ull)f2bf(f2.w) << 48);
        v23.y =  (ull)f2bf(f3.x) | ((ull)f2bf(f3.y) << 16) | ((ull)f2bf(f3.z) << 32) | ((ull)f2bf(f3.w) << 48);
        ull* dst = (ull*)(wsB + off);
        *(ullx2*)(dst)     = v01;
        *(ullx2*)(dst + 2) = v23;
    }
}

// ---------- Main GEMM: 128x128 tile, BK=32, 32x32x16 bf16 MFMA,
//            XOR swizzle on (row>>1)&3 -> conflict-free per 32-lane phase,
//            global_load_lds width=16 staging, scatter epilogue w/ sibling zeroing. ----------
__global__ __launch_bounds__(256) void gemm_kernel(
    const unsigned short* __restrict__ wsA, const unsigned short* __restrict__ wsB,
    const int* __restrict__ indices, float* __restrict__ out)
{
    __shared__ __align__(16) unsigned short As[128 * 32];
    __shared__ __align__(16) unsigned short Bs[128 * 32];

    const int tid  = threadIdx.x;
    const int lane = tid & 63;
    const int wave = tid >> 6;
    const int wm   = wave >> 1;   // row quadrant (64 rows)
    const int wn   = wave & 1;    // col quadrant (64 cols)
    const int l31  = lane & 31;
    const int h    = lane >> 5;   // k-half of fragment

    const int r0 = blockIdx.y * 128;
    const int b0 = blockIdx.x * 128;

    // staging: lane -> LDS row wave*32+call*16+(lane>>2), phys col16 = lane&3.
    // swizzle phys = logical ^ ((row>>1)&3); (row>>1)&3 == (lane>>3)&3 for both calls.
    // => source logical col16 = (lane&3) ^ ((lane>>3)&3)  (permutes within quad's 64B window)
    const int srow   = wave * 32 + (lane >> 2);
    const int scol16 = (lane & 3) ^ ((lane >> 3) & 3);
    const unsigned ldsOff = wave * 2048;
    const unsigned short* gA = wsA + (size_t)(r0 + srow) * KLOG + scol16 * 8;
    const unsigned short* gB = wsB + (size_t)(b0 + srow) * KLOG + scol16 * 8;

    f32x16 acc[2][2];
#pragma unroll
    for (int i = 0; i < 2; ++i)
#pragma unroll
        for (int j = 0; j < 2; ++j)
#pragma unroll
            for (int e = 0; e < 16; ++e) acc[i][j][e] = 0.f;

    for (int k0 = 0; k0 < KLOG; k0 += 32) {
        gload_lds16(gA + k0,             (char*)As + ldsOff);
        gload_lds16(gA + 16 * KLOG + k0, (char*)As + ldsOff + 1024);
        gload_lds16(gB + k0,             (char*)Bs + ldsOff);
        gload_lds16(gB + 16 * KLOG + k0, (char*)Bs + ldsOff + 1024);
        __syncthreads();

        // fragments: logical col16 = kh*2+h, phys = logical ^ ((row>>1)&3)
        bf16x8 a[2][2], b[2][2];
#pragma unroll
        for (int mi = 0; mi < 2; ++mi)
#pragma unroll
            for (int kh = 0; kh < 2; ++kh) {
                const int row = wm * 64 + mi * 32 + l31;
                const int phys = (kh * 2 + h) ^ ((row >> 1) & 3);
                a[mi][kh] = __builtin_bit_cast(bf16x8, *(const s16x8*)(As + row * 32 + phys * 8));
            }
#pragma unroll
        for (int nj = 0; nj < 2; ++nj)
#pragma unroll
            for (int kh = 0; kh < 2; ++kh) {
                const int row = wn * 64 + nj * 32 + l31;
                const int phys = (kh * 2 + h) ^ ((row >> 1) & 3);
                b[nj][kh] = __builtin_bit_cast(bf16x8, *(const s16x8*)(Bs + row * 32 + phys * 8));
            }

#pragma unroll
        for (int kh = 0; kh < 2; ++kh)
#pragma unroll
            for (int mi = 0; mi < 2; ++mi)
#pragma unroll
                for (int nj = 0; nj < 2; ++nj)
                    acc[mi][nj] = __builtin_amdgcn_mfma_f32_32x32x16_bf16(
                                      a[mi][kh], b[nj][kh], acc[mi][nj], 0, 0, 0);
        __syncthreads();
    }

    // epilogue: C/D (32x32): col = l31, row = (reg&3) + 8*(reg>>2) + 4*h  [m74/m101]
#pragma unroll
    for (int mi = 0; mi < 2; ++mi) {
#pragma unroll
        for (int reg = 0; reg < 16; ++reg) {
            const int rloc = wm * 64 + mi * 32 + (reg & 3) + 8 * (reg >> 2) + 4 * h;
            const int L = indices[r0 + rloc];
            const size_t base  = (size_t)L * NB;
            const size_t baseZ = (size_t)(L ^ 1) * NB;
#pragma unroll
            for (int nj = 0; nj < 2; ++nj) {
                const int col = b0 + wn * 64 + nj * 32 + l31;
                out[base  + col] = acc[mi][nj][reg];
                out[baseZ + col] = 0.0f;
            }
        }
    }
}

// ---------- Fallback (round-1 fused kernel) if ws is too small ----------
__global__ __launch_bounds__(256) void spmm_dt_fallback(
    const float* __restrict__ weight, const int* __restrict__ indices,
    const int* __restrict__ metadata, const float* __restrict__ input,
    float* __restrict__ out)
{
    __shared__ __align__(16) unsigned short As[128][32];
    __shared__ __align__(16) unsigned short Bs[128][32];
    const int tid = threadIdx.x, lane = tid & 63, wave = tid >> 6;
    const int wm = wave >> 1, wn = wave & 1, l15 = lane & 15, quad = lane >> 4;
    const int r0 = blockIdx.y * 128, b0 = blockIdx.x * 128;
    f32x4 acc[4][4];
#pragma unroll
    for (int i = 0; i < 4; ++i)
#pragma unroll
        for (int j = 0; j < 4; ++j) acc[i][j] = (f32x4){0.f, 0.f, 0.f, 0.f};
    const int srow = tid >> 3, sgrp = tid & 7;
    for (int kk = 0; kk < KLOG / 32; ++kk) {
        const int c0 = kk * 16, k0 = kk * 32;
#pragma unroll
        for (int s = 0; s < 4; ++s) {
            const int row = srow + s * 32;
            const size_t off = (size_t)(r0 + row) * IN_F + c0 + 2 * sgrp;
            const float2 w = *(const float2*)(weight + off);
            const int2  md = *(const int2*)(metadata + off);
            *(ull*)(&As[row][4 * sgrp]) =
                ((ull)f2bf(w.x) << (md.x * 16)) | ((ull)f2bf(w.y) << (md.y * 16));
        }
#pragma unroll
        for (int s = 0; s < 4; ++s) {
            const int row = srow + s * 32;
            const float4 f = *(const float4*)(&input[(size_t)(b0 + row) * KLOG + k0 + sgrp * 4]);
            *(ull*)(&Bs[row][sgrp * 4]) =
                 (ull)f2bf(f.x) | ((ull)f2bf(f.y) << 16) |
                ((ull)f2bf(f.z) << 32) | ((ull)f2bf(f.w) << 48);
        }
        __syncthreads();
        bf16x8 a[4], b[4];
#pragma unroll
        for (int i = 0; i < 4; ++i)
            a[i] = __builtin_bit_cast(bf16x8, *(const s16x8*)(&As[wm * 64 + i * 16 + l15][quad * 8]));
#pragma unroll
        for (int j = 0; j < 4; ++j)
            b[j] = __builtin_bit_cast(bf16x8, *(const s16x8*)(&Bs[wn * 64 + j * 16 + l15][quad * 8]));
#pragma unroll
        for (int i = 0; i < 4; ++i)
#pragma unroll
            for (int j = 0; j < 4; ++j)
                acc[i][j] = __builtin_amdgcn_mfma_f32_16x16x32_bf16(a[i], b[j], acc[i][j], 0, 0, 0);
        __syncthreads();
    }
#pragma unroll
    for (int i = 0; i < 4; ++i)
#pragma unroll
        for (int t = 0; t < 4; ++t) {
            const int r = r0 + wm * 64 + i * 16 + quad * 4 + t;
            const int L = indices[r];
            const size_t base = (size_t)L * NB, baseZ = (size_t)(L ^ 1) * NB;
#pragma unroll
            for (int j = 0; j < 4; ++j) {
                const int col = b0 + wn * 64 + j * 16 + l15;
                out[base + col] = acc[i][j][t];
                out[baseZ + col] = 0.0f;
            }
        }
}

extern "C" void kernel_launch(void* const* d_in, const int* in_sizes, int n_in,
                              void* d_out, int out_size, void* d_ws, size_t ws_size,
                              hipStream_t stream) {
    const float* weight   = (const float*)d_in[0];
    const int*   indices  = (const int*)d_in[1];
    const int*   metadata = (const int*)d_in[2];
    const float* input    = (const float*)d_in[3];
    float*       out      = (float*)d_out;

    const size_t needA = (size_t)OUT_F * KLOG * 2;  // 32 MB
    const size_t needB = (size_t)NB * KLOG * 2;     // 32 MB
    if (ws_size >= needA + needB) {
        unsigned short* wsA = (unsigned short*)d_ws;
        unsigned short* wsB = wsA + (size_t)OUT_F * KLOG;
        prep_kernel<<<dim3(8192), dim3(256), 0, stream>>>(weight, metadata, input, wsA, wsB);
        gemm_kernel<<<dim3(NB / 128, OUT_F / 128), dim3(256), 0, stream>>>(wsA, wsB, indices, out);
    } else {
        spmm_dt_fallback<<<dim3(NB / 128, OUT_F / 128), dim3(256), 0, stream>>>(
            weight, indices, metadata, input, out);
    }
}